// Round 7
// baseline (161.617 us; speedup 1.0000x reference)
//
#include <hip/hip_runtime.h>
#include <hip/hip_bf16.h>

// retina_polar2: log-polar glimpse sampling + 10x10 avg-pool
// x: [64,3,512,512] f32 | l_t_prev: [64,2] f32 | grid_2d: [320,640,2] f32
// out: [64,3,32,64] f32
//
// Round-7: LDS-staged gathers. TA wall is ~1 lane-addr/cy/CU for divergent
// global gathers (measured r4->r6); LDS pipe is ~10x faster per lane.
// Per image: 44 blocks = polar bands sized so the touched region fits a
// [3][64x64] f32 LDS tile:
//   A: win 0-14  x 160th (4 blocks)   B: win 15-21 x 80th (8)
//   C: win 22-26 x 40th (16)          D: win 27-31 x 40th (16, won't fit
//      -> auto-fallback to round-6 direct float4-pair global path)
// bbox computed EXACTLY per block (coords monotone in radial index per
// theta column -> endpoints suffice); staging clamps source coords to the
// border, which reproduces padding_mode='border' for the +1 taps for free.

#define HI_ 512
#define WI_ 512
#define B_  64
#define PLANE_ (HI_ * WI_)

__device__ __forceinline__ float sel4(float4 f, int k) {
    const float a  = (k & 2) ? f.z : f.x;
    const float b2 = (k & 2) ? f.w : f.y;
    return (k & 1) ? b2 : a;
}

template<int TW, int NW>
__device__ __forceinline__ void processBand(
    const int b, const int slot, const int w0,
    const float* __restrict__ x,
    const float* __restrict__ grid,
    float* __restrict__ out,
    const float sx, const float sy,
    float* __restrict__ simg,   // [3][4096] f32, pitch 64
    float* __restrict__ sacc,   // >= 3*NW*(TW/10)
    int*   __restrict__ sbb)    // [4]
{
    constexpr int TC   = TW / 10;
    constexpr int ACCN = 3 * NW * TC;
    constexpr int ITEMS = TW * NW * 2;     // (theta, win, rr-half)
    const int tid = threadIdx.x;
    const int th0 = slot * TW;

    for (int i = tid; i < ACCN; i += 256) sacc[i] = 0.0f;
    if (tid < 2) sbb[tid] = 0x7F800000;    // +inf bits (mnx, mny)
    if (tid >= 2 && tid < 4) sbb[tid] = 0; // (mxx, mxy)
    __syncthreads();

    // ---- exact bbox: endpoints rr = rh*5, rh*5+4 (monotone in rr) ----
    float mnx = 1e30f, mny = 1e30f, mxx = 0.0f, mxy = 0.0f;
    for (int it = tid; it < ITEMS; it += 256) {
        const int rh  = it & 1;
        const int u   = it >> 1;
        const int th  = u % TW;
        const int win = u / TW;
        const int grow = (w0 + win) * 10 + rh * 5;
        #pragma unroll
        for (int e = 0; e < 2; ++e) {
            const float2 g = *reinterpret_cast<const float2*>(
                grid + ((size_t)(grow + e * 4) * 640 + th0 + th) * 2);
            const float ix = fminf(fmaxf(fmaf(g.x, 256.0f, sx), 0.0f), 511.0f);
            const float iy = fminf(fmaxf(fmaf(g.y, 256.0f, sy), 0.0f), 511.0f);
            mnx = fminf(mnx, ix); mxx = fmaxf(mxx, ix);
            mny = fminf(mny, iy); mxy = fmaxf(mxy, iy);
        }
    }
    atomicMin(&sbb[0], __float_as_int(mnx));
    atomicMin(&sbb[1], __float_as_int(mny));
    atomicMax(&sbb[2], __float_as_int(mxx));
    atomicMax(&sbb[3], __float_as_int(mxy));
    __syncthreads();

    const int x0b = (int)floorf(__int_as_float(sbb[0]));
    const int y0b = (int)floorf(__int_as_float(sbb[1]));
    const int x1b = (int)floorf(__int_as_float(sbb[2])) + 1;
    const int y1b = (int)floorf(__int_as_float(sbb[3])) + 1;
    const int W = x1b - x0b + 1;
    const int H = y1b - y0b + 1;
    const bool fits = (W <= 64) && (H <= 64);

    const float* __restrict__ xb = x + (size_t)b * 3 * PLANE_;

    // ---- stage (border-clamped source => free 'border' padding) ----
    if (fits) {
        const int tot = H << 6;
        for (int i = tid; i < tot; i += 256) {
            const int ysrc = min(y0b + (i >> 6), HI_ - 1);
            const int xsrc = min(x0b + (i & 63), WI_ - 1);
            const int a = ysrc * WI_ + xsrc;
            simg[i]            = xb[a];
            simg[4096 + i]     = xb[a + PLANE_];
            simg[2 * 4096 + i] = xb[a + 2 * PLANE_];
        }
    }
    __syncthreads();

    // ---- gather ----
    for (int it = tid; it < ITEMS; it += 256) {
        const int rh  = it & 1;
        const int u   = it >> 1;
        const int th  = u % TW;
        const int win = u / TW;
        const int col = th / 10;
        const int grow0 = (w0 + win) * 10 + rh * 5;
        float s0 = 0.0f, s1 = 0.0f, s2 = 0.0f;

        if (fits) {
            #pragma unroll
            for (int j = 0; j < 5; ++j) {
                const float2 g = *reinterpret_cast<const float2*>(
                    grid + ((size_t)(grow0 + j) * 640 + th0 + th) * 2);
                const float ix = fminf(fmaxf(fmaf(g.x, 256.0f, sx), 0.0f), 511.0f);
                const float iy = fminf(fmaxf(fmaf(g.y, 256.0f, sy), 0.0f), 511.0f);
                const float x0f = floorf(ix);
                const float y0f = floorf(iy);
                const float wx = ix - x0f;
                const float wy = iy - y0f;
                const int off = (((int)y0f - y0b) << 6) + ((int)x0f - x0b);
                const float w11 = wx * wy;
                const float w10 = wy - w11;
                const float w01 = wx - w11;
                const float w00 = 1.0f - wx - wy + w11;
                {
                    const float* p = simg + off;
                    s0 += p[0]*w00 + p[1]*w01 + p[64]*w10 + p[65]*w11;
                }
                {
                    const float* p = simg + 4096 + off;
                    s1 += p[0]*w00 + p[1]*w01 + p[64]*w10 + p[65]*w11;
                }
                {
                    const float* p = simg + 2*4096 + off;
                    s2 += p[0]*w00 + p[1]*w01 + p[64]*w10 + p[65]*w11;
                }
            }
        } else {
            // round-6 direct path: float4 pair loads (2 addrs/sample/ch)
            int   apk[5];
            float wxv[5], wyv[5];
            #pragma unroll
            for (int j = 0; j < 5; ++j) {
                const float2 g = *reinterpret_cast<const float2*>(
                    grid + ((size_t)(grow0 + j) * 640 + th0 + th) * 2);
                const float ix = fminf(fmaxf(fmaf(g.x, 256.0f, sx), 0.0f), 511.0f);
                const float iy = fminf(fmaxf(fmaf(g.y, 256.0f, sy), 0.0f), 511.0f);
                const float x0f = floorf(ix);
                const float y0f = floorf(iy);
                const int x0 = (int)x0f;
                const int y0 = (int)y0f;
                const int dx1 = min(x0 + 1, WI_ - 1) - x0;   // 0/1
                const int dy1 = min(y0 + 1, HI_ - 1) - y0;   // 0/1
                const int xe  = min(x0 & ~1, WI_ - 4);
                const int q   = x0 - xe;                      // 0..3
                apk[j] = (y0 * WI_ + xe) | (q << 18) | (dx1 << 20) | (dy1 << 21);
                wxv[j] = ix - x0f;
                wyv[j] = iy - y0f;
            }
            float sc[3];
            #pragma unroll
            for (int c = 0; c < 3; ++c) {
                const float* __restrict__ xc = xb + (size_t)c * PLANE_;
                float4 f0[5], f1[5];
                #pragma unroll
                for (int j = 0; j < 5; ++j) {
                    const int pk  = apk[j];
                    const int Ae  = pk & 0x3FFFF;
                    const int dyo = (pk >> 12) & 512;   // bit21 -> +512
                    f0[j] = *reinterpret_cast<const float4*>(xc + Ae);
                    f1[j] = *reinterpret_cast<const float4*>(xc + Ae + dyo);
                }
                float a = 0.0f;
                #pragma unroll
                for (int j = 0; j < 5; ++j) {
                    const int pk = apk[j];
                    const int q  = (pk >> 18) & 3;
                    const int i1 = q + ((pk >> 20) & 1);
                    const float v00 = sel4(f0[j], q);
                    const float v01 = sel4(f0[j], i1);
                    const float v10 = sel4(f1[j], q);
                    const float v11 = sel4(f1[j], i1);
                    const float w11 = wxv[j] * wyv[j];
                    const float w10 = wyv[j] - w11;
                    const float w01 = wxv[j] - w11;
                    const float w00 = 1.0f - wxv[j] - wyv[j] + w11;
                    a += v00*w00 + v01*w01 + v10*w10 + v11*w11;
                }
                sc[c] = a;
            }
            s0 = sc[0]; s1 = sc[1]; s2 = sc[2];
        }

        atomicAdd(&sacc[0 * NW * TC + win * TC + col], s0);
        atomicAdd(&sacc[1 * NW * TC + win * TC + col], s1);
        atomicAdd(&sacc[2 * NW * TC + win * TC + col], s2);
    }
    __syncthreads();

    // ---- output ----
    for (int i = tid; i < ACCN; i += 256) {
        const int c   = i / (NW * TC);
        const int rem = i - c * (NW * TC);
        const int win = rem / TC;
        const int col = rem - win * TC;
        out[(((size_t)b * 3 + c) * 32 + w0 + win) * 64 + slot * TC + col] =
            sacc[i] * 0.01f;
    }
}

__global__ __launch_bounds__(256) void retina_polar_staged(
    const float* __restrict__ x,
    const float* __restrict__ lt,
    const float* __restrict__ grid,
    float* __restrict__ out)
{
    __shared__ float simg[3 * 4096];
    __shared__ float sacc[720];
    __shared__ int   sbb[4];

    const int bid = blockIdx.x;
    const int b   = bid / 44;
    const int r   = bid - b * 44;
    const float sx = fmaf(lt[b * 2 + 0], 256.0f, 255.5f);
    const float sy = fmaf(lt[b * 2 + 1], 256.0f, 255.5f);

    if (r < 4)
        processBand<160, 15>(b, r,      0,  x, grid, out, sx, sy, simg, sacc, sbb);
    else if (r < 12)
        processBand<80, 7>(b, r - 4,   15, x, grid, out, sx, sy, simg, sacc, sbb);
    else if (r < 28)
        processBand<40, 5>(b, r - 12,  22, x, grid, out, sx, sy, simg, sacc, sbb);
    else
        processBand<40, 5>(b, r - 28,  27, x, grid, out, sx, sy, simg, sacc, sbb);
}

extern "C" void kernel_launch(void* const* d_in, const int* in_sizes, int n_in,
                              void* d_out, int out_size, void* d_ws, size_t ws_size,
                              hipStream_t stream)
{
    const float* x    = (const float*)d_in[0];
    const float* lt   = (const float*)d_in[1];
    const float* grid = (const float*)d_in[2];
    float* out        = (float*)d_out;

    retina_polar_staged<<<dim3(B_ * 44), dim3(256), 0, stream>>>(x, lt, grid, out);
}

// Round 8
// 109.549 us; speedup vs baseline: 1.4753x; 1.4753x over previous
//
#include <hip/hip_runtime.h>
#include <hip/hip_bf16.h>

// retina_polar2: log-polar glimpse sampling + 10x10 avg-pool
// x: [64,3,512,512] f32 | l_t_prev: [64,2] f32 | grid_2d: [320,640,2] f32
// out: [64,3,32,64] f32
//
// Round-8: LDS staging done right.
//  - TA wall (~1 scattered lane-addr/cy/CU, measured r4->r6) is escaped by
//    gathering from LDS; staging is float4-coalesced (cheap on TA).
//  - bbox per block is ANALYTIC (gx=r sin t, gy=r cos t; exact range over
//    the band rectangle + 0.5px margin) -> no extra grid pass. grid VALUES
//    still come from grid_2d. Offset clamps are a safety net.
//  - 9 bands (G windows x T theta cols) sized so every staged region fits
//    [3][64][68] f32 LDS (52.2 KB, 3 blocks/CU). No fallback path.

#define HI_ 512
#define WI_ 512
#define B_  64
#define PLANE_ (HI_ * WI_)
#define PITCH 68
#define LDSCH (64 * PITCH)   // 4352 f32 per channel

template<int W0, int G, int T>
__device__ __forceinline__ void band(
    const int b, const int slot,
    const float* __restrict__ x,
    const float* __restrict__ grid,
    float* __restrict__ out,
    const float sx, const float sy,
    float* __restrict__ simg,   // [3][64][68]
    float* __restrict__ sacc)   // [3*G*(T/10)]
{
    constexpr int TC    = T / 10;
    constexpr int ITEMS = T * G * 2;      // (theta, win, radial-half)
    constexpr int ACCN  = 3 * G * TC;
    const int tid = threadIdx.x;
    const int th0 = slot * T;

    for (int i = tid; i < ACCN; i += 256) sacc[i] = 0.0f;

    // ---- analytic bbox of the band (exact range of r*sin, r*cos) ----
    const float CT  = 6.283185307179586f / 640.0f;
    const float tha = th0 * CT, thb = (th0 + T - 1) * CT;
    const float LN001 = -4.605170185988091f;       // ln 0.01
    const float LSTEP = 4.0943445622221004f / 319.0f; // ln 60 / 319
    const float r_lo  = expf(fmaf((float)(10 * W0),           LSTEP, LN001));
    const float r_hi  = expf(fmaf((float)(10 * (W0 + G) - 1), LSTEP, LN001));
    const float plo = 256.0f * r_lo, phi = 256.0f * r_hi;

    const float sa = sinf(tha), sb = sinf(thb);
    const float ca = cosf(tha), cb = cosf(thb);
    const float smax = (tha < 1.5707965f && thb > 1.5707962f) ?  1.0f : fmaxf(sa, sb);
    const float smin = (tha < 4.7123892f && thb > 4.7123888f) ? -1.0f : fminf(sa, sb);
    const float cmax = fmaxf(ca, cb);   // theta=0 only at a slice endpoint
    const float cmin = (tha < 3.1415928f && thb > 3.1415925f) ? -1.0f : fminf(ca, cb);

    const float ixmin = fminf(fminf(plo*smin, phi*smin), fminf(plo*smax, phi*smax)) + sx;
    const float ixmax = fmaxf(fmaxf(plo*smin, phi*smin), fmaxf(plo*smax, phi*smax)) + sx;
    const float iymin = fminf(fminf(plo*cmin, phi*cmin), fminf(plo*cmax, phi*cmax)) + sy;
    const float iymax = fmaxf(fmaxf(plo*cmin, phi*cmin), fmaxf(plo*cmax, phi*cmax)) + sy;

    const int x_lo = max(0, (int)floorf(ixmin - 0.5f));
    const int x_hi = min(511, (int)ceilf(ixmax + 0.5f));
    const int y_lo = max(0, (int)floorf(iymin - 0.5f));
    const int y_hi = min(511, (int)ceilf(iymax + 0.5f));

    const int xs4 = x_lo & ~3;
    const int W4  = min(PITCH / 4, ((x_hi + 1 - xs4) >> 2) + 1);
    const int H   = min(64, y_hi - y_lo + 2);
    const int wmax = (W4 << 2) - 2;
    const int hmax = H - 2;

    const float* __restrict__ xb = x + (size_t)b * 3 * PLANE_;

    // ---- stage: float4-coalesced, border-cloned at right/bottom edge ----
    const int perCh = H * W4;
    for (int i = tid; i < 3 * perCh; i += 256) {
        const int c   = i / perCh;
        const int rem = i - c * perCh;
        const int row = rem / W4;
        const int c4  = rem - row * W4;
        const int ys  = min(y_lo + row, 511);
        const int xb0 = xs4 + (c4 << 2);
        const float* __restrict__ src = xb + (size_t)c * PLANE_ + ys * 512;
        float4 v;
        if (xb0 <= 508) {
            v = *reinterpret_cast<const float4*>(src + xb0);
        } else {
            v.x = src[min(xb0,     511)];
            v.y = src[min(xb0 + 1, 511)];
            v.z = src[min(xb0 + 2, 511)];
            v.w = src[min(xb0 + 3, 511)];
        }
        *reinterpret_cast<float4*>(&simg[c * LDSCH + row * PITCH + (c4 << 2)]) = v;
    }
    __syncthreads();

    // ---- gather from LDS ----
    for (int it = tid; it < ITEMS; it += 256) {
        const int tl   = it % T;
        const int u    = it / T;
        const int rh   = u & 1;
        const int win  = u >> 1;
        const int grow = (W0 + win) * 10 + rh * 5;

        int   offc[5];
        float wxv[5], wyv[5];
        #pragma unroll
        for (int j = 0; j < 5; ++j) {
            const float2 g = *reinterpret_cast<const float2*>(
                grid + ((size_t)(grow + j) * 640 + th0 + tl) * 2);
            const float ix = fminf(fmaxf(fmaf(g.x, 256.0f, sx), 0.0f), 511.0f);
            const float iy = fminf(fmaxf(fmaf(g.y, 256.0f, sy), 0.0f), 511.0f);
            const float x0f = floorf(ix);
            const float y0f = floorf(iy);
            const int col = min(max((int)x0f - xs4, 0), wmax);
            const int row = min(max((int)y0f - y_lo, 0), hmax);
            offc[j] = row * PITCH + col;
            wxv[j] = ix - x0f;
            wyv[j] = iy - y0f;
        }

        float sc[3];
        #pragma unroll
        for (int c = 0; c < 3; ++c) {
            const float* __restrict__ pc = simg + c * LDSCH;
            float v00[5], v01[5], v10[5], v11[5];
            #pragma unroll
            for (int j = 0; j < 5; ++j) {
                const float* __restrict__ p = pc + offc[j];
                v00[j] = p[0];
                v01[j] = p[1];
                v10[j] = p[PITCH];
                v11[j] = p[PITCH + 1];
            }
            float a = 0.0f;
            #pragma unroll
            for (int j = 0; j < 5; ++j) {
                const float w11 = wxv[j] * wyv[j];
                const float w10 = wyv[j] - w11;
                const float w01 = wxv[j] - w11;
                const float w00 = 1.0f - wxv[j] - wyv[j] + w11;
                a += v00[j]*w00 + v01[j]*w01 + v10[j]*w10 + v11[j]*w11;
            }
            sc[c] = a;
        }

        const int tc = tl / 10;
        atomicAdd(&sacc[(0 * G + win) * TC + tc], sc[0]);
        atomicAdd(&sacc[(1 * G + win) * TC + tc], sc[1]);
        atomicAdd(&sacc[(2 * G + win) * TC + tc], sc[2]);
    }
    __syncthreads();

    // ---- output ----
    for (int i = tid; i < ACCN; i += 256) {
        const int c   = i / (G * TC);
        const int rem = i - c * (G * TC);
        const int win = rem / TC;
        const int tc  = rem - win * TC;
        out[(((size_t)b * 3 + c) * 32 + W0 + win) * 64 + th0 / 10 + tc] =
            sacc[i] * 0.01f;
    }
}

__global__ __launch_bounds__(256) void retina_polar_staged(
    const float* __restrict__ x,
    const float* __restrict__ lt,
    const float* __restrict__ grid,
    float* __restrict__ out)
{
    __shared__ float simg[3 * LDSCH];   // 52224 B
    __shared__ float sacc[96];

    const int bid = blockIdx.x;
    const int b   = bid / 176;
    const int r   = bid - b * 176;
    const float sx = fmaf(lt[b * 2 + 0], 256.0f, 255.5f);
    const float sy = fmaf(lt[b * 2 + 1], 256.0f, 255.5f);

    if      (r <  16) band< 0, 8, 40>(b, r,       x, grid, out, sx, sy, simg, sacc);
    else if (r <  32) band< 8, 7, 40>(b, r - 16,  x, grid, out, sx, sy, simg, sacc);
    else if (r <  48) band<15, 5, 40>(b, r - 32,  x, grid, out, sx, sy, simg, sacc);
    else if (r <  64) band<20, 4, 40>(b, r - 48,  x, grid, out, sx, sy, simg, sacc);
    else if (r <  80) band<24, 3, 40>(b, r - 64,  x, grid, out, sx, sy, simg, sacc);
    else if (r <  96) band<27, 2, 40>(b, r - 80,  x, grid, out, sx, sy, simg, sacc);
    else if (r < 112) band<29, 1, 40>(b, r - 96,  x, grid, out, sx, sy, simg, sacc);
    else if (r < 144) band<30, 1, 20>(b, r - 112, x, grid, out, sx, sy, simg, sacc);
    else              band<31, 1, 20>(b, r - 144, x, grid, out, sx, sy, simg, sacc);
}

extern "C" void kernel_launch(void* const* d_in, const int* in_sizes, int n_in,
                              void* d_out, int out_size, void* d_ws, size_t ws_size,
                              hipStream_t stream)
{
    const float* x    = (const float*)d_in[0];
    const float* lt   = (const float*)d_in[1];
    const float* grid = (const float*)d_in[2];
    float* out        = (float*)d_out;

    retina_polar_staged<<<dim3(B_ * 176), dim3(256), 0, stream>>>(x, lt, grid, out);
}

// Round 9
// 93.643 us; speedup vs baseline: 1.7259x; 1.1699x over previous
//
#include <hip/hip_runtime.h>
#include <hip/hip_fp16.h>

// retina_polar2: log-polar glimpse sampling + 10x10 avg-pool
// x: [64,3,512,512] f32 | l_t_prev: [64,2] f32 | grid_2d: [320,640,2] f32
// out: [64,3,32,64] f32
//
// Round-9: LDS staging, tuned.
//  - Channel-interleaved f16 tile [64][68][{c0,c1,c2,pad}] -> ONE
//    ds_read_b64 per bilinear tap yields all 3 channels (12 -> 4 LDS
//    instrs/sample); tile 34.8 KB -> 4 blocks/CU (16 waves, was 12).
//  - Division-free staging (row=tid>>4, col=tid&15 stepping), float4
//    coalesced global reads, f32->f16 convert on store.
//  - Analytic bbox (exact sin/cos range over the band) as in r8.
//  - Bands: 8 groups, outermost two windows merged -> 144 blocks/image.

#define HI_ 512
#define WI_ 512
#define B_  64
#define PLANE_ (HI_ * WI_)
#define PITCH 68
#define TILEPIX (64 * PITCH)   // 4352 pixels; x4 halves = 34816 B

// decode packed {c0,c1,c2,pad} f16 pixel (8 B, one ds_read_b64)
__device__ __forceinline__ void dec3(const __half* s, int pix,
                                     float& a, float& b, float& c) {
    const uint2 q = *reinterpret_cast<const uint2*>(s + 4 * pix);
    const __half2 h01 = *reinterpret_cast<const __half2*>(&q.x);
    const float2 f = __half22float2(h01);
    const unsigned short hu = (unsigned short)(q.y & 0xffffu);
    a = f.x; b = f.y;
    c = __half2float(*reinterpret_cast<const __half*>(&hu));
}

template<int W0, int G, int T>
__device__ __forceinline__ void band(
    const int b, const int slot,
    const float* __restrict__ x,
    const float* __restrict__ grid,
    float* __restrict__ out,
    const float sx, const float sy,
    __half* __restrict__ simg,   // [TILEPIX][4] f16
    float*  __restrict__ sacc)   // [3*G*(T/10)]
{
    constexpr int TC    = T / 10;
    constexpr int ITEMS = T * G * 2;      // (theta, win, radial-half)
    constexpr int ACCN  = 3 * G * TC;
    const int tid = threadIdx.x;
    const int th0 = slot * T;

    if (tid < ACCN) sacc[tid] = 0.0f;

    // ---- analytic bbox of the band (exact range of r*sin, r*cos) ----
    const float CT  = 6.283185307179586f / 640.0f;
    const float tha = th0 * CT, thb = (th0 + T - 1) * CT;
    const float LN001 = -4.605170185988091f;          // ln 0.01
    const float LSTEP = 4.0943445622221004f / 319.0f; // ln 60 / 319
    const float r_lo  = expf(fmaf((float)(10 * W0),           LSTEP, LN001));
    const float r_hi  = expf(fmaf((float)(10 * (W0 + G) - 1), LSTEP, LN001));
    const float plo = 256.0f * r_lo, phi = 256.0f * r_hi;

    const float sa = sinf(tha), sb = sinf(thb);
    const float ca = cosf(tha), cb = cosf(thb);
    const float smax = (tha < 1.5707965f && thb > 1.5707962f) ?  1.0f : fmaxf(sa, sb);
    const float smin = (tha < 4.7123892f && thb > 4.7123888f) ? -1.0f : fminf(sa, sb);
    const float cmax = fmaxf(ca, cb);
    const float cmin = (tha < 3.1415928f && thb > 3.1415925f) ? -1.0f : fminf(ca, cb);

    const float ixmin = fminf(fminf(plo*smin, phi*smin), fminf(plo*smax, phi*smax)) + sx;
    const float ixmax = fmaxf(fmaxf(plo*smin, phi*smin), fmaxf(plo*smax, phi*smax)) + sx;
    const float iymin = fminf(fminf(plo*cmin, phi*cmin), fminf(plo*cmax, phi*cmax)) + sy;
    const float iymax = fmaxf(fmaxf(plo*cmin, phi*cmin), fmaxf(plo*cmax, phi*cmax)) + sy;

    const int x_lo = max(0, (int)floorf(ixmin - 0.5f));
    const int x_hi = min(511, (int)ceilf(ixmax + 0.5f));
    const int y_lo = max(0, (int)floorf(iymin - 0.5f));
    const int y_hi = min(511, (int)ceilf(iymax + 0.5f));

    const int xs4 = x_lo & ~3;
    const int W4  = min(PITCH / 4, ((x_hi + 1 - xs4) >> 2) + 1);
    const int H   = min(64, y_hi - y_lo + 2);
    const int wmax = (W4 << 2) - 2;
    const int hmax = H - 2;

    const float* __restrict__ xb = x + (size_t)b * 3 * PLANE_;

    // ---- stage: division-free, float4-coalesced, f16 interleaved ----
    const int lane16 = tid & 15;
    const int rowB   = tid >> 4;           // 0..15
    for (int row = rowB; row < H; row += 16) {
        const int ys = min(y_lo + row, 511);
        const float* __restrict__ r0 = xb + ys * 512;
        for (int c4 = lane16; c4 < W4; c4 += 16) {
            const int xb0 = xs4 + (c4 << 2);
            float v0[4], v1[4], v2[4];
            if (xb0 <= 508) {
                *reinterpret_cast<float4*>(v0) = *reinterpret_cast<const float4*>(r0 + xb0);
                *reinterpret_cast<float4*>(v1) = *reinterpret_cast<const float4*>(r0 + PLANE_ + xb0);
                *reinterpret_cast<float4*>(v2) = *reinterpret_cast<const float4*>(r0 + 2 * PLANE_ + xb0);
            } else {
                #pragma unroll
                for (int p = 0; p < 4; ++p) {
                    const int xs = min(xb0 + p, 511);
                    v0[p] = r0[xs];
                    v1[p] = r0[PLANE_ + xs];
                    v2[p] = r0[2 * PLANE_ + xs];
                }
            }
            const int pix0 = row * PITCH + (c4 << 2);
            #pragma unroll
            for (int p = 0; p < 4; ++p) {
                __half* d = simg + 4 * (pix0 + p);
                *reinterpret_cast<__half2*>(d) = __floats2half2_rn(v0[p], v1[p]);
                d[2] = __float2half_rn(v2[p]);
            }
        }
    }
    __syncthreads();

    // ---- gather from LDS (4 x ds_read_b64 per sample) ----
    for (int it = tid; it < ITEMS; it += 256) {
        const int tl   = it % T;
        const int u    = it / T;
        const int rh   = u & 1;
        const int win  = u >> 1;
        const int grow = (W0 + win) * 10 + rh * 5;

        int   pp[5];
        float wxv[5], wyv[5];
        #pragma unroll
        for (int j = 0; j < 5; ++j) {
            const float2 g = *reinterpret_cast<const float2*>(
                grid + ((size_t)(grow + j) * 640 + th0 + tl) * 2);
            const float ix = fminf(fmaxf(fmaf(g.x, 256.0f, sx), 0.0f), 511.0f);
            const float iy = fminf(fmaxf(fmaf(g.y, 256.0f, sy), 0.0f), 511.0f);
            const float x0f = floorf(ix);
            const float y0f = floorf(iy);
            const int col = min(max((int)x0f - xs4, 0), wmax);
            const int row = min(max((int)y0f - y_lo, 0), hmax);
            pp[j] = row * PITCH + col;
            wxv[j] = ix - x0f;
            wyv[j] = iy - y0f;
        }

        float s0 = 0.0f, s1 = 0.0f, s2 = 0.0f;
        #pragma unroll
        for (int j = 0; j < 5; ++j) {
            float a00,b00,c00, a01,b01,c01, a10,b10,c10, a11,b11,c11;
            dec3(simg, pp[j],             a00, b00, c00);
            dec3(simg, pp[j] + 1,         a01, b01, c01);
            dec3(simg, pp[j] + PITCH,     a10, b10, c10);
            dec3(simg, pp[j] + PITCH + 1, a11, b11, c11);
            const float w11 = wxv[j] * wyv[j];
            const float w10 = wyv[j] - w11;
            const float w01 = wxv[j] - w11;
            const float w00 = 1.0f - wxv[j] - wyv[j] + w11;
            s0 += a00*w00 + a01*w01 + a10*w10 + a11*w11;
            s1 += b00*w00 + b01*w01 + b10*w10 + b11*w11;
            s2 += c00*w00 + c01*w01 + c10*w10 + c11*w11;
        }

        const int tc = tl / 10;
        atomicAdd(&sacc[(0 * G + win) * TC + tc], s0);
        atomicAdd(&sacc[(1 * G + win) * TC + tc], s1);
        atomicAdd(&sacc[(2 * G + win) * TC + tc], s2);
    }
    __syncthreads();

    // ---- output (ACCN <= 96 < 256: single pass, const divisors) ----
    if (tid < ACCN) {
        const int c   = tid / (G * TC);
        const int rem = tid - c * (G * TC);
        const int win = rem / TC;
        const int tc  = rem - win * TC;
        out[(((size_t)b * 3 + c) * 32 + W0 + win) * 64 + (th0 / 10) + tc] =
            sacc[tid] * 0.01f;
    }
}

__global__ __launch_bounds__(256, 4) void retina_polar_staged(
    const float* __restrict__ x,
    const float* __restrict__ lt,
    const float* __restrict__ grid,
    float* __restrict__ out)
{
    __shared__ __half simg[TILEPIX * 4];   // 34816 B
    __shared__ float  sacc[96];

    const int bid = blockIdx.x;
    const int b   = bid / 144;
    const int r   = bid - b * 144;
    const float sx = fmaf(lt[b * 2 + 0], 256.0f, 255.5f);
    const float sy = fmaf(lt[b * 2 + 1], 256.0f, 255.5f);

    if      (r <  16) band< 0, 8, 40>(b, r,       x, grid, out, sx, sy, simg, sacc);
    else if (r <  32) band< 8, 7, 40>(b, r - 16,  x, grid, out, sx, sy, simg, sacc);
    else if (r <  48) band<15, 5, 40>(b, r - 32,  x, grid, out, sx, sy, simg, sacc);
    else if (r <  64) band<20, 4, 40>(b, r - 48,  x, grid, out, sx, sy, simg, sacc);
    else if (r <  80) band<24, 3, 40>(b, r - 64,  x, grid, out, sx, sy, simg, sacc);
    else if (r <  96) band<27, 2, 40>(b, r - 80,  x, grid, out, sx, sy, simg, sacc);
    else if (r < 112) band<29, 1, 40>(b, r - 96,  x, grid, out, sx, sy, simg, sacc);
    else              band<30, 2, 20>(b, r - 112, x, grid, out, sx, sy, simg, sacc);
}

extern "C" void kernel_launch(void* const* d_in, const int* in_sizes, int n_in,
                              void* d_out, int out_size, void* d_ws, size_t ws_size,
                              hipStream_t stream)
{
    const float* x    = (const float*)d_in[0];
    const float* lt   = (const float*)d_in[1];
    const float* grid = (const float*)d_in[2];
    float* out        = (float*)d_out;

    retina_polar_staged<<<dim3(B_ * 144), dim3(256), 0, stream>>>(x, lt, grid, out);
}

// Round 10
// 76.970 us; speedup vs baseline: 2.0997x; 1.2166x over previous
//
#include <hip/hip_runtime.h>
#include <hip/hip_fp16.h>

// retina_polar2: log-polar glimpse sampling + 10x10 avg-pool
// x: [64,3,512,512] f32 | l_t_prev: [64,2] f32 | grid_2d: [320,640,2] f32
// out: [64,3,32,64] f32
//
// Round-10: VALU diet on the r9 LDS-staged structure.
//  - Interior fast path (analytic bbox >= 1px inside image -> skip all
//    per-sample clamps; only border-touching blocks pay them).
//  - Item = (theta, win) with all 10 radial samples per thread -> half the
//    item overhead and half the LDS atomics (10 per output-ch, was 20).
//  - Channel-pair f16 decode straight to float2, float2 accumulator
//    (SLP-friendly for v_pk_fma_f32).
//  - f16 channel-interleaved tile [64][68][{c0,c1,c2,pad}], one
//    ds_read_b64 per tap; 34.8 KB -> 4 blocks/CU.

#define HI_ 512
#define WI_ 512
#define B_  64
#define PLANE_ (HI_ * WI_)
#define PITCH 68
#define TILEPIX (64 * PITCH)   // 4352 pixels * 8 B = 34816 B

__device__ __forceinline__ void dec3(const __half* __restrict__ s, int pix,
                                     float2& f01, float& c) {
    const uint2 q = *reinterpret_cast<const uint2*>(s + 4 * pix);
    f01 = __half22float2(*reinterpret_cast<const __half2*>(&q.x));
    const unsigned short hu = (unsigned short)(q.y & 0xffffu);
    c = __half2float(*reinterpret_cast<const __half*>(&hu));
}

template<int W0, int G, int T, bool INT>
__device__ __forceinline__ void gatherLoop(
    const int tid, const int th0,
    const float* __restrict__ grid,
    const __half* __restrict__ simg,
    float* __restrict__ sacc,
    const float sx, const float sy,
    const int xs4, const int y_lo, const int wmax, const int hmax)
{
    constexpr int TC    = T / 10;
    constexpr int ITEMS = T * G;
    for (int it = tid; it < ITEMS; it += 256) {
        const int tl   = it % T;
        const int win  = it / T;
        const int grow = (W0 + win) * 10;

        int   pp [10];
        float wxv[10], wyv[10];
        #pragma unroll
        for (int j = 0; j < 10; ++j) {
            const float2 g = *reinterpret_cast<const float2*>(
                grid + ((size_t)(grow + j) * 640 + th0 + tl) * 2);
            float ix = fmaf(g.x, 256.0f, sx);
            float iy = fmaf(g.y, 256.0f, sy);
            if (!INT) {
                ix = fminf(fmaxf(ix, 0.0f), 511.0f);
                iy = fminf(fmaxf(iy, 0.0f), 511.0f);
            }
            const float x0f = floorf(ix);
            const float y0f = floorf(iy);
            int col = (int)x0f - xs4;
            int row = (int)y0f - y_lo;
            if (!INT) {
                col = min(max(col, 0), wmax);
                row = min(max(row, 0), hmax);
            }
            pp [j] = row * PITCH + col;
            wxv[j] = ix - x0f;
            wyv[j] = iy - y0f;
        }

        float2 s01 = make_float2(0.0f, 0.0f);
        float  s2  = 0.0f;
        #pragma unroll
        for (int hh = 0; hh < 2; ++hh) {
            float2 f00[5], f01v[5], f10[5], f11[5];
            float  c00[5], c01[5], c10[5], c11[5];
            #pragma unroll
            for (int j = 0; j < 5; ++j) {
                const int p = pp[hh * 5 + j];
                dec3(simg, p,             f00[j],  c00[j]);
                dec3(simg, p + 1,         f01v[j], c01[j]);
                dec3(simg, p + PITCH,     f10[j],  c10[j]);
                dec3(simg, p + PITCH + 1, f11[j],  c11[j]);
            }
            #pragma unroll
            for (int j = 0; j < 5; ++j) {
                const int rr = hh * 5 + j;
                const float w11 = wxv[rr] * wyv[rr];
                const float w10 = wyv[rr] - w11;
                const float w01 = wxv[rr] - w11;
                const float w00 = 1.0f - wxv[rr] - wyv[rr] + w11;
                s01.x += f00[j].x*w00 + f01v[j].x*w01 + f10[j].x*w10 + f11[j].x*w11;
                s01.y += f00[j].y*w00 + f01v[j].y*w01 + f10[j].y*w10 + f11[j].y*w11;
                s2    += c00[j]  *w00 + c01[j]  *w01 + c10[j]  *w10 + c11[j]  *w11;
            }
        }

        const int tc = tl / 10;
        atomicAdd(&sacc[(0 * G + win) * TC + tc], s01.x);
        atomicAdd(&sacc[(1 * G + win) * TC + tc], s01.y);
        atomicAdd(&sacc[(2 * G + win) * TC + tc], s2);
    }
}

template<int W0, int G, int T>
__device__ __forceinline__ void band(
    const int b, const int slot,
    const float* __restrict__ x,
    const float* __restrict__ grid,
    float* __restrict__ out,
    const float sx, const float sy,
    __half* __restrict__ simg,
    float*  __restrict__ sacc)
{
    constexpr int TC   = T / 10;
    constexpr int ACCN = 3 * G * TC;
    const int tid = threadIdx.x;
    const int th0 = slot * T;

    if (tid < ACCN) sacc[tid] = 0.0f;

    // ---- analytic bbox (exact range of 256*r*sin/cos over the band) ----
    const float CT  = 6.283185307179586f / 640.0f;
    const float tha = th0 * CT, thb = (th0 + T - 1) * CT;
    const float LN001 = -4.605170185988091f;          // ln 0.01
    const float LSTEP = 4.0943445622221004f / 319.0f; // ln 60 / 319
    const float r_lo  = expf(fmaf((float)(10 * W0),           LSTEP, LN001));
    const float r_hi  = expf(fmaf((float)(10 * (W0 + G) - 1), LSTEP, LN001));
    const float plo = 256.0f * r_lo, phi = 256.0f * r_hi;

    const float sa = sinf(tha), sb = sinf(thb);
    const float ca = cosf(tha), cb = cosf(thb);
    const float smax = (tha < 1.5707965f && thb > 1.5707962f) ?  1.0f : fmaxf(sa, sb);
    const float smin = (tha < 4.7123892f && thb > 4.7123888f) ? -1.0f : fminf(sa, sb);
    const float cmax = fmaxf(ca, cb);
    const float cmin = (tha < 3.1415928f && thb > 3.1415925f) ? -1.0f : fminf(ca, cb);

    const float ixmin = fminf(fminf(plo*smin, phi*smin), fminf(plo*smax, phi*smax)) + sx;
    const float ixmax = fmaxf(fmaxf(plo*smin, phi*smin), fmaxf(plo*smax, phi*smax)) + sx;
    const float iymin = fminf(fminf(plo*cmin, phi*cmin), fminf(plo*cmax, phi*cmax)) + sy;
    const float iymax = fmaxf(fmaxf(plo*cmin, phi*cmin), fmaxf(plo*cmax, phi*cmax)) + sy;

    const int x_lo = max(0, (int)floorf(ixmin - 0.5f));
    const int x_hi = min(511, (int)ceilf(ixmax + 0.5f));
    const int y_lo = max(0, (int)floorf(iymin - 0.5f));
    const int y_hi = min(511, (int)ceilf(iymax + 0.5f));

    const int xs4 = x_lo & ~3;
    const int W4  = min(PITCH / 4, ((x_hi + 1 - xs4) >> 2) + 1);
    const int H   = min(64, y_hi - y_lo + 2);
    const int wmax = (W4 << 2) - 2;
    const int hmax = H - 2;

    // clamps provably no-ops when bbox is strictly inside the image
    const bool interior = (ixmin > 1.0f) && (ixmax < 510.0f) &&
                          (iymin > 1.0f) && (iymax < 510.0f);

    const float* __restrict__ xb = x + (size_t)b * 3 * PLANE_;

    // ---- stage: division-free, float4-coalesced, f16 interleaved ----
    const int lane16 = tid & 15;
    const int rowB   = tid >> 4;
    for (int row = rowB; row < H; row += 16) {
        const int ys = min(y_lo + row, 511);
        const float* __restrict__ r0 = xb + ys * 512;
        for (int c4 = lane16; c4 < W4; c4 += 16) {
            const int xb0 = xs4 + (c4 << 2);
            float v0[4], v1[4], v2[4];
            if (xb0 <= 508) {
                *reinterpret_cast<float4*>(v0) = *reinterpret_cast<const float4*>(r0 + xb0);
                *reinterpret_cast<float4*>(v1) = *reinterpret_cast<const float4*>(r0 + PLANE_ + xb0);
                *reinterpret_cast<float4*>(v2) = *reinterpret_cast<const float4*>(r0 + 2 * PLANE_ + xb0);
            } else {
                #pragma unroll
                for (int p = 0; p < 4; ++p) {
                    const int xs = min(xb0 + p, 511);
                    v0[p] = r0[xs];
                    v1[p] = r0[PLANE_ + xs];
                    v2[p] = r0[2 * PLANE_ + xs];
                }
            }
            const int pix0 = row * PITCH + (c4 << 2);
            #pragma unroll
            for (int p = 0; p < 4; ++p) {
                __half* d = simg + 4 * (pix0 + p);
                *reinterpret_cast<__half2*>(d) = __floats2half2_rn(v0[p], v1[p]);
                d[2] = __float2half_rn(v2[p]);
            }
        }
    }
    __syncthreads();

    if (interior)
        gatherLoop<W0, G, T, true >(tid, th0, grid, simg, sacc, sx, sy, xs4, y_lo, wmax, hmax);
    else
        gatherLoop<W0, G, T, false>(tid, th0, grid, simg, sacc, sx, sy, xs4, y_lo, wmax, hmax);
    __syncthreads();

    if (tid < ACCN) {
        const int c   = tid / (G * TC);
        const int rem = tid - c * (G * TC);
        const int win = rem / TC;
        const int tc  = rem - win * TC;
        out[(((size_t)b * 3 + c) * 32 + W0 + win) * 64 + (th0 / 10) + tc] =
            sacc[tid] * 0.01f;
    }
}

__global__ __launch_bounds__(256, 4) void retina_polar_staged(
    const float* __restrict__ x,
    const float* __restrict__ lt,
    const float* __restrict__ grid,
    float* __restrict__ out)
{
    __shared__ __half simg[TILEPIX * 4];   // 34816 B
    __shared__ float  sacc[96];

    const int bid = blockIdx.x;
    const int b   = bid / 144;
    const int r   = bid - b * 144;
    const float sx = fmaf(lt[b * 2 + 0], 256.0f, 255.5f);
    const float sy = fmaf(lt[b * 2 + 1], 256.0f, 255.5f);

    if      (r <  16) band< 0, 8, 40>(b, r,       x, grid, out, sx, sy, simg, sacc);
    else if (r <  32) band< 8, 7, 40>(b, r - 16,  x, grid, out, sx, sy, simg, sacc);
    else if (r <  48) band<15, 5, 40>(b, r - 32,  x, grid, out, sx, sy, simg, sacc);
    else if (r <  64) band<20, 4, 40>(b, r - 48,  x, grid, out, sx, sy, simg, sacc);
    else if (r <  80) band<24, 3, 40>(b, r - 64,  x, grid, out, sx, sy, simg, sacc);
    else if (r <  96) band<27, 2, 40>(b, r - 80,  x, grid, out, sx, sy, simg, sacc);
    else if (r < 112) band<29, 1, 40>(b, r - 96,  x, grid, out, sx, sy, simg, sacc);
    else              band<30, 2, 20>(b, r - 112, x, grid, out, sx, sy, simg, sacc);
}

extern "C" void kernel_launch(void* const* d_in, const int* in_sizes, int n_in,
                              void* d_out, int out_size, void* d_ws, size_t ws_size,
                              hipStream_t stream)
{
    const float* x    = (const float*)d_in[0];
    const float* lt   = (const float*)d_in[1];
    const float* grid = (const float*)d_in[2];
    float* out        = (float*)d_out;

    retina_polar_staged<<<dim3(B_ * 144), dim3(256), 0, stream>>>(x, lt, grid, out);
}